// Round 3
// baseline (50.137 us; speedup 1.0000x reference)
//
#include <hip/hip_runtime.h>
#include <hip/hip_bf16.h>

// out[8192,1024] = x[8192,1024] @ W[1024,1024]^T + b  (fp32 in/out, bf16 MFMA compute)
// v3: 256 threads (4 waves), BM=64 x BN=128 tile -> grid 1024 (4 blocks/CU, all
// resident, independent barrier domains). XCD-exclusive mtile mapping so x-panels
// are single-XCD (L2-reuse). XOR-swizzled bf16 LDS stripes: conflict-free ds_write,
// 2-way (free) ds_read_b128. Depth-2 named-set register prefetch, dbuf LDS.

typedef float f32x4 __attribute__((ext_vector_type(4)));
typedef __bf16 bf16x8 __attribute__((ext_vector_type(8)));
typedef unsigned short u16x4 __attribute__((ext_vector_type(4)));
typedef unsigned short u16x8 __attribute__((ext_vector_type(8)));

#define MD 8192
#define ND 1024
#define KD 1024
#define BM 64
#define BN 128
#define BK 32
#define NT (KD / BK)      // 32 K-steps
#define THREADS 256

__device__ __forceinline__ u16x4 cvt4(f32x4 v) {
  u16x4 o;
#pragma unroll
  for (int i = 0; i < 4; ++i) o[i] = __builtin_bit_cast(unsigned short, (__bf16)v[i]);
  return o;
}

__global__ __launch_bounds__(THREADS, 4)
void linear_mfma_v3(const float* __restrict__ X, const float* __restrict__ W,
                    const float* __restrict__ Bv, float* __restrict__ C) {
  // bf16 tiles, stripe layout: stripe = row>>4 (1024 B each), within-stripe byte
  // = ((k>>3)*256 + (row&15)*16 + (k&7)*2) ^ ((k>>3)<<5)   [XOR swizzle]
  __shared__ __align__(16) char Asm[2][BM * BK * 2];   // 4 KB each
  __shared__ __align__(16) char Bsm[2][BN * BK * 2];   // 8 KB each

  const int bid = blockIdx.x;
  const int xcd = bid & 7;          // dispatch round-robins XCD by bid&7
  const int ord = bid >> 3;         // 0..127
  const int mtile = xcd * 16 + (ord >> 3);   // XCD-exclusive m-panels
  const int ntile = ord & 7;
  const int brow = mtile * BM;
  const int bcol = ntile * BN;

  const int t = threadIdx.x;
  const int lane = t & 63;
  const int w = t >> 6;             // 0..3 ; wave covers cols w*32..w*32+31

  // ---- staging params: quad q covers (row = q>>3, k-chunk sc = q&7)
  const float* gA[2]; int woffA[2];
#pragma unroll
  for (int i = 0; i < 2; ++i) {
    int q = t + i * THREADS;        // 0..511
    int row = q >> 3, sc = q & 7;
    gA[i] = X + (size_t)(brow + row) * KD + sc * 4;
    woffA[i] = (row >> 4) * 1024 +
               ((((sc >> 1) * 256) + ((row & 15) * 16) + ((sc & 1) * 8)) ^ ((sc >> 1) << 5));
  }
  const float* gB[4]; int woffB[4];
#pragma unroll
  for (int i = 0; i < 4; ++i) {
    int q = t + i * THREADS;        // 0..1023
    int row = q >> 3, sc = q & 7;
    gB[i] = W + (size_t)(bcol + row) * KD + sc * 4;
    woffB[i] = (row >> 4) * 1024 +
               ((((sc >> 1) * 256) + ((row & 15) * 16) + ((sc & 1) * 8)) ^ ((sc >> 1) << 5));
  }

  // fragment read offset within a stripe (16 B per lane, swizzle-mirrored)
  const int fr = (lane * 16) ^ ((lane >> 4) << 5);

  // depth-2 prefetch register sets (literal first index -> static)
  f32x4 pa[2][2], pb[2][4];

#define LOADSET(S, kt)                                                          \
  do {                                                                          \
    _Pragma("unroll") for (int i = 0; i < 2; ++i)                               \
        pa[S][i] = *(const f32x4*)(gA[i] + (size_t)(kt) * BK);                  \
    _Pragma("unroll") for (int i = 0; i < 4; ++i)                               \
        pb[S][i] = *(const f32x4*)(gB[i] + (size_t)(kt) * BK);                  \
  } while (0)

#define WRITESET(buf, S)                                                        \
  do {                                                                          \
    _Pragma("unroll") for (int i = 0; i < 2; ++i)                               \
        *(u16x4*)&Asm[buf][woffA[i]] = cvt4(pa[S][i]);                          \
    _Pragma("unroll") for (int i = 0; i < 4; ++i)                               \
        *(u16x4*)&Bsm[buf][woffB[i]] = cvt4(pb[S][i]);                          \
  } while (0)

  f32x4 acc[4][2] = {};

#define COMPUTE(buf)                                                            \
  do {                                                                          \
    bf16x8 af[4], bfr[2];                                                       \
    _Pragma("unroll") for (int m = 0; m < 4; ++m) {                             \
      u16x8 v = *(const u16x8*)(&Asm[buf][m * 1024 + fr]);                      \
      af[m] = __builtin_bit_cast(bf16x8, v);                                    \
    }                                                                           \
    _Pragma("unroll") for (int n = 0; n < 2; ++n) {                             \
      u16x8 v = *(const u16x8*)(&Bsm[buf][(w * 2 + n) * 1024 + fr]);            \
      bfr[n] = __builtin_bit_cast(bf16x8, v);                                   \
    }                                                                           \
    _Pragma("unroll") for (int m = 0; m < 4; ++m)                               \
      _Pragma("unroll") for (int n = 0; n < 2; ++n)                             \
        acc[m][n] = __builtin_amdgcn_mfma_f32_16x16x32_bf16(af[m], bfr[n],      \
                                                            acc[m][n], 0, 0, 0);\
  } while (0)

  // ---- prologue
  LOADSET(0, 0);
  LOADSET(1, 1);
  WRITESET(0, 0);
  __syncthreads();

  // ---- main loop: 2 K-steps per iteration
#pragma unroll 1
  for (int kt2 = 0; kt2 < NT / 2; ++kt2) {
    // EVEN step kt = 2*kt2 (reads LDS buf0); set0 free -> prefetch kt+2
    if (kt2 < NT / 2 - 1) LOADSET(0, 2 * kt2 + 2);
    COMPUTE(0);
    WRITESET(1, 1);                 // data for kt = 2*kt2+1
    __syncthreads();

    // ODD step kt = 2*kt2+1 (reads buf1); set1 free -> prefetch kt+3
    if (kt2 < NT / 2 - 1) LOADSET(1, 2 * kt2 + 3);
    COMPUTE(1);
    if (kt2 < NT / 2 - 1) WRITESET(0, 0);   // data for kt = 2*kt2+2
    __syncthreads();
  }

  // ---- epilogue: C/D layout col = lane&15, row = (lane>>4)*4 + j
  const int rbase = brow + ((lane >> 4) << 2);
  const int cbase = bcol + w * 32 + (lane & 15);
#pragma unroll
  for (int n = 0; n < 2; ++n) {
    const int col = cbase + n * 16;
    const float bv = Bv[col];
#pragma unroll
    for (int m = 0; m < 4; ++m) {
      const int row = rbase + m * 16;
#pragma unroll
      for (int j = 0; j < 4; ++j) {
        C[(size_t)(row + j) * ND + col] = acc[m][n][j] + bv;
      }
    }
  }
}

extern "C" void kernel_launch(void* const* d_in, const int* in_sizes, int n_in,
                              void* d_out, int out_size, void* d_ws, size_t ws_size,
                              hipStream_t stream) {
  const float* x = (const float*)d_in[0];   // [8192,1024] f32
  const float* W = (const float*)d_in[1];   // [1024,1024] f32
  const float* b = (const float*)d_in[2];   // [1024] f32
  float* out = (float*)d_out;               // [8192,1024] f32

  dim3 grid((MD / BM) * (ND / BN));   // 128 * 8 = 1024
  dim3 block(THREADS);
  hipLaunchKernelGGL(linear_mfma_v3, grid, block, 0, stream, x, W, b, out);
}

// Round 4
// 36.166 us; speedup vs baseline: 1.3863x; 1.3863x over previous
//
#include <hip/hip_runtime.h>
#include <hip/hip_bf16.h>

// out[8192,1024] = x[8192,1024] @ W[1024,1024]^T + b  (fp32 in/out, bf16 MFMA)
// v4: BM=BN=128, BK=64, 512 thr / 8 waves (2x4), one barrier per K-step (16 total),
// XCD-exclusive m-panels, swizzled bf16 LDS (conflict-free write AND read),
// depth-1 reg prefetch issued at top of each K-step. LDS 64KB -> 2 blocks/CU.

typedef float f32x4 __attribute__((ext_vector_type(4)));
typedef __bf16 bf16x8 __attribute__((ext_vector_type(8)));
typedef unsigned short u16x4 __attribute__((ext_vector_type(4)));
typedef unsigned short u16x8 __attribute__((ext_vector_type(8)));

#define MD 8192
#define ND 1024
#define KD 1024
#define BM 128
#define BN 128
#define BK 64
#define NT (KD / BK)     // 16 K-steps
#define THREADS 512

// LDS tile layout (bf16 [128 rows][64 k], 16KB):
//   stripe = row>>4 (2048 B each)
//   within-stripe: ks=k>>5, kq=(k>>3)&3, r16=row&15, ko=k&7
//   byte = (ks<<10) + (kq<<8) + (((r16 ^ kq ^ (ks<<2)) & 15)<<4) + ko*2
// Write (8B/thread): one row's 8 (ks,kq) slots land on 8 distinct banksets -> conflict-free.
// Frag read (16B/lane): lane-permutation of 64 consecutive slots -> conflict-free.

__device__ __forceinline__ u16x4 cvt4(f32x4 v) {
  u16x4 o;
#pragma unroll
  for (int i = 0; i < 4; ++i) o[i] = __builtin_bit_cast(unsigned short, (__bf16)v[i]);
  return o;
}

__global__ __launch_bounds__(THREADS, 4)
void linear_mfma_v4(const float* __restrict__ X, const float* __restrict__ W,
                    const float* __restrict__ Bv, float* __restrict__ C) {
  __shared__ __align__(16) char Asm[2][BM * BK * 2];   // 16 KB each
  __shared__ __align__(16) char Bsm[2][BN * BK * 2];   // 16 KB each

  const int bid = blockIdx.x;
  const int xcd = bid & 7;                   // dispatch round-robins XCDs by bid&7
  const int ord = bid >> 3;                  // 0..63
  const int mtile = xcd * 8 + (ord >> 3);    // 8 XCD-exclusive m-panels per XCD
  const int ntile = ord & 7;
  const int brow = mtile * BM;
  const int bcol = ntile * BN;

  const int t = threadIdx.x;
  const int lane = t & 63;
  const int w = t >> 6;      // 0..7
  const int wr = w >> 2;     // 0..1 : 64-row half
  const int wc = w & 3;      // 0..3 : 32-col quarter

  // ---- staging: q = t + i*512 -> (row = q>>4, sc = q&15); 4 chunks each for A and B
  const float* gA[4];
  const float* gB[4];
  int woff[4];
#pragma unroll
  for (int i = 0; i < 4; ++i) {
    int q = t + i * THREADS;
    int row = q >> 4, sc = q & 15;
    int ks = sc >> 3, kq = (sc >> 1) & 3, h = sc & 1;
    gA[i] = X + (size_t)(brow + row) * KD + sc * 4;
    gB[i] = W + (size_t)(bcol + row) * KD + sc * 4;
    woff[i] = (row >> 4) * 2048 + (ks << 10) + (kq << 8) +
              ((((row & 15) ^ kq ^ (ks << 2)) & 15) << 4) + h * 8;
  }

  // fragment read lane-offsets per ks
  int lbase[2];
#pragma unroll
  for (int ks = 0; ks < 2; ++ks)
    lbase[ks] = (ks << 10) + ((lane >> 4) << 8) +
                ((((lane & 15) ^ (lane >> 4) ^ (ks << 2)) & 15) << 4);

  f32x4 pa[4], pb[4];

#define LOADT(kt)                                                         \
  do {                                                                    \
    _Pragma("unroll") for (int i = 0; i < 4; ++i)                         \
        pa[i] = *(const f32x4*)(gA[i] + (size_t)(kt) * BK);               \
    _Pragma("unroll") for (int i = 0; i < 4; ++i)                         \
        pb[i] = *(const f32x4*)(gB[i] + (size_t)(kt) * BK);               \
  } while (0)

#define WRITET(buf)                                                       \
  do {                                                                    \
    _Pragma("unroll") for (int i = 0; i < 4; ++i)                         \
        *(u16x4*)&Asm[buf][woff[i]] = cvt4(pa[i]);                        \
    _Pragma("unroll") for (int i = 0; i < 4; ++i)                         \
        *(u16x4*)&Bsm[buf][woff[i]] = cvt4(pb[i]);                        \
  } while (0)

  f32x4 acc[4][2] = {};

#define COMPUTE(buf)                                                           \
  do {                                                                         \
    _Pragma("unroll") for (int ks = 0; ks < 2; ++ks) {                         \
      bf16x8 b0 = __builtin_bit_cast(bf16x8,                                   \
          *(const u16x8*)(&Bsm[buf][(wc * 2 + 0) * 2048 + lbase[ks]]));        \
      bf16x8 b1 = __builtin_bit_cast(bf16x8,                                   \
          *(const u16x8*)(&Bsm[buf][(wc * 2 + 1) * 2048 + lbase[ks]]));        \
      _Pragma("unroll") for (int m = 0; m < 4; ++m) {                          \
        bf16x8 am = __builtin_bit_cast(bf16x8,                                 \
            *(const u16x8*)(&Asm[buf][(wr * 4 + m) * 2048 + lbase[ks]]));      \
        acc[m][0] = __builtin_amdgcn_mfma_f32_16x16x32_bf16(am, b0, acc[m][0], 0, 0, 0); \
        acc[m][1] = __builtin_amdgcn_mfma_f32_16x16x32_bf16(am, b1, acc[m][1], 0, 0, 0); \
      }                                                                        \
    }                                                                          \
  } while (0)

  // ---- prologue
  LOADT(0);
  WRITET(0);
  __syncthreads();

  // ---- main loop: one barrier per K-step
#pragma unroll 1
  for (int kt = 0; kt < NT; ++kt) {
    if (kt + 1 < NT) LOADT(kt + 1);          // issue next-tile loads early
    COMPUTE(kt & 1);
    if (kt + 1 < NT) {
      WRITET((kt + 1) & 1);                  // cvt + stage next tile
      __syncthreads();
    }
  }

  // ---- epilogue: C/D layout col = lane&15, row = (lane>>4)*4 + j  [m89]
  const int rbase = brow + wr * 64 + ((lane >> 4) << 2);
  const int cbase = bcol + wc * 32 + (lane & 15);
#pragma unroll
  for (int n = 0; n < 2; ++n) {
    const int col = cbase + n * 16;
    const float bv = Bv[col];
#pragma unroll
    for (int m = 0; m < 4; ++m) {
      const int row = rbase + m * 16;
#pragma unroll
      for (int j = 0; j < 4; ++j) {
        C[(size_t)(row + j) * ND + col] = acc[m][n][j] + bv;
      }
    }
  }
}

extern "C" void kernel_launch(void* const* d_in, const int* in_sizes, int n_in,
                              void* d_out, int out_size, void* d_ws, size_t ws_size,
                              hipStream_t stream) {
  const float* x = (const float*)d_in[0];   // [8192,1024] f32
  const float* W = (const float*)d_in[1];   // [1024,1024] f32
  const float* b = (const float*)d_in[2];   // [1024] f32
  float* out = (float*)d_out;               // [8192,1024] f32

  dim3 grid((MD / BM) * (ND / BN));   // 64 * 8 = 512
  dim3 block(THREADS);
  hipLaunchKernelGGL(linear_mfma_v4, grid, block, 0, stream, x, W, b, out);
}